// Round 1
// baseline (370.761 us; speedup 1.0000x reference)
//
#include <hip/hip_runtime.h>
#include <hip/hip_bf16.h>

#define NNODES 50000
#define NEDGES 150000
#define DFEAT  512
#define HID    512
#define NCLS   47

typedef __hip_bfloat16 bf16;
typedef __attribute__((ext_vector_type(8))) short short8;
typedef __attribute__((ext_vector_type(4))) float float4v;

typedef const __attribute__((address_space(1))) unsigned int* gas_t;
typedef __attribute__((address_space(3))) unsigned int* las_t;
__device__ __forceinline__ void load_lds16(const void* g, void* l) {
    __builtin_amdgcn_global_load_lds((gas_t)g, (las_t)l, 16, 0, 0);
}

__device__ __forceinline__ float bfbits_lo(unsigned int w) {
    return __uint_as_float((w & 0xFFFFu) << 16);
}
__device__ __forceinline__ float bfbits_hi(unsigned int w) {
    return __uint_as_float(w & 0xFFFF0000u);
}

// ---------------- dtype detection (1 block, 64 threads) ----------------
__global__ void k_detect(const void* x, const void* ei, int* flags) {
    __shared__ int scnt[64], sor[64];
    int t = threadIdx.x;
    const unsigned short* xs = (const unsigned short*)x;
    int c = 0;
    for (int i = t; i < 256; i += 64) {
        unsigned int e = (xs[2 * i] >> 7) & 0xFF;
        c += (e >= 117 && e <= 130) ? 1 : 0;
    }
    const int* w = (const int*)ei;
    int o = 0;
    for (int i = 2 * t + 1; i < 512; i += 128) o |= w[i];
    scnt[t] = c; sor[t] = o;
    __syncthreads();
    if (t == 0) {
        int C = 0, O = 0;
        for (int i = 0; i < 64; i++) { C += scnt[i]; O |= sor[i]; }
        flags[0] = (C > 128) ? 1 : 0;
        flags[1] = (O == 0) ? 1 : 0;
    }
}

__device__ __forceinline__ int eidx(const void* ei, int half, int e, int is64) {
    if (is64) return (int)((const long long*)ei)[(size_t)half * NEDGES + e];
    return ((const int*)ei)[half * NEDGES + e];
}

// ---------------- utility ----------------
__global__ void k_zero32(unsigned int* p, size_t n) {
    size_t i = (size_t)blockIdx.x * blockDim.x + threadIdx.x;
    if (i < n) p[i] = 0u;
}

__global__ void k_cvt(const void* src, float* dst, int n, const int* flags) {
    int i = blockIdx.x * blockDim.x + threadIdx.x;
    if (i >= n) return;
    dst[i] = flags[0] ? __bfloat162float(((const bf16*)src)[i]) : ((const float*)src)[i];
}

// W1 [K=512][N=512] -> W1T bf16 [N][K]
__global__ void k_cvt_w1t(const void* W1, bf16* W1T, const int* flags) {
    int i = blockIdx.x * blockDim.x + threadIdx.x;
    if (i >= DFEAT * HID) return;
    int k = i / HID, n = i % HID;
    float v = flags[0] ? __bfloat162float(((const bf16*)W1)[i]) : ((const float*)W1)[i];
    W1T[(size_t)n * DFEAT + k] = __float2bfloat16(v);
}

// W2 [K=512][N=47] -> W2T bf16 [64][512] zero-padded
__global__ void k_cvt_w2t(const void* W2, bf16* W2T, const int* flags) {
    int i = blockIdx.x * blockDim.x + threadIdx.x;
    if (i >= 64 * HID) return;
    int n = i / HID, k = i % HID;
    float v = 0.0f;
    if (n < NCLS) {
        size_t idx = (size_t)k * NCLS + n;
        v = flags[0] ? __bfloat162float(((const bf16*)W2)[idx]) : ((const float*)W2)[idx];
    }
    W2T[(size_t)n * HID + k] = __float2bfloat16(v);
}

// ---------------- graph structure ----------------
__global__ void k_count(const void* ei, int* cnt, const int* flags) {
    int e = blockIdx.x * blockDim.x + threadIdx.x;
    if (e >= NEDGES) return;
    atomicAdd(&cnt[eidx(ei, 1, e, flags[1])], 1);
}

__global__ void k_dinv(const int* cnt, float* dinv) {
    int i = blockIdx.x * blockDim.x + threadIdx.x;
    if (i < NNODES) dinv[i] = rsqrtf(1.0f + (float)cnt[i]);
}

__global__ __launch_bounds__(256) void k_scan_part(const int* cnt, int* part) {
    __shared__ int s[256];
    int i = blockIdx.x * 256 + threadIdx.x;
    s[threadIdx.x] = (i < NNODES) ? cnt[i] : 0;
    __syncthreads();
    for (int off = 128; off > 0; off >>= 1) {
        if (threadIdx.x < off) s[threadIdx.x] += s[threadIdx.x + off];
        __syncthreads();
    }
    if (threadIdx.x == 0) part[blockIdx.x] = s[0];
}

__global__ __launch_bounds__(256) void k_scan_off(int* part, int n) {
    __shared__ int s[256];
    int v = (threadIdx.x < n) ? part[threadIdx.x] : 0;
    s[threadIdx.x] = v;
    __syncthreads();
    for (int off = 1; off < 256; off <<= 1) {
        int t = (threadIdx.x >= off) ? s[threadIdx.x - off] : 0;
        __syncthreads();
        s[threadIdx.x] += t;
        __syncthreads();
    }
    if (threadIdx.x < n) part[threadIdx.x] = s[threadIdx.x] - v;
}

__global__ __launch_bounds__(256) void k_scan_fin(const int* cnt, const int* part,
                                                  int* rowptr, int* cursor) {
    __shared__ int s[256];
    int i = blockIdx.x * 256 + threadIdx.x;
    int v = (i < NNODES) ? cnt[i] : 0;
    s[threadIdx.x] = v;
    __syncthreads();
    for (int off = 1; off < 256; off <<= 1) {
        int t = (threadIdx.x >= off) ? s[threadIdx.x - off] : 0;
        __syncthreads();
        s[threadIdx.x] += t;
        __syncthreads();
    }
    int incl = s[threadIdx.x] + part[blockIdx.x];
    if (i < NNODES) {
        rowptr[i + 1] = incl;
        cursor[i] = incl - v;
    }
    if (i == 0) rowptr[0] = 0;
}

__global__ void k_fill(const void* ei, int* cursor, int* csr_src, const int* flags) {
    int e = blockIdx.x * blockDim.x + threadIdx.x;
    if (e >= NEDGES) return;
    int is64 = flags[1];
    int v = eidx(ei, 1, e, is64);
    int u = eidx(ei, 0, e, is64);
    int pos = atomicAdd(&cursor[v], 1);
    csr_src[pos] = u;
}

// ---------------- GEMM1 v4: 128x128, XOR-swizzled LDS, XCD-aware remap,
// 2-phase double-buffered prefetch (T3-lite): issue next K-tile's
// global_load_lds BEFORE computing the current tile, so the single
// __syncthreads() (vmcnt(0)+barrier) per iteration only pays the residual
// of (HBM latency - compute time). Buffer-reuse safe with ONE barrier/iter:
// all ds_reads of buf[cur] are consumed by MFMAs (lgkmcnt-drained) before
// the barrier, so the next iteration may overwrite buf[cur].
__global__ __launch_bounds__(256, 2) void k_gemm1_v4(
    const void* __restrict__ X, const bf16* __restrict__ W1T,
    bf16* __restrict__ h1c, int c0, int C, const int* __restrict__ flags,
    int col_tiles, int rows_per_xcd, int n_row_tiles) {
    const int b = blockIdx.x;
    const int xcd = b & 7;
    const int s = b >> 3;
    const int col_t = s % col_tiles;
    const int lr = s / col_tiles;
    const int row_t = xcd * rows_per_xcd + lr;
    if (row_t >= n_row_tiles) return;

    __shared__ bf16 As[2][128 * 64];   // 2 x 16 KiB
    __shared__ bf16 Bs[2][128 * 64];   // 2 x 16 KiB  -> 64 KiB total, 2 blocks/CU
    const int tid = threadIdx.x;
    const int wave = tid >> 6, lane = tid & 63;
    const int row0 = row_t * 128;
    const int gc0 = c0 + col_t * 128;
    const int isb = flags[0];

    float4v acc[2][8];
#pragma unroll
    for (int i = 0; i < 2; i++)
#pragma unroll
        for (int j = 0; j < 8; j++) acc[i][j] = (float4v){0.f, 0.f, 0.f, 0.f};

    const int rb = wave * 32;
    const int frow = lane & 15;
    const int fk = lane >> 4;

    auto stageAB = [&](int k0, bf16* Asb, bf16* Bsb) {
        if (isb) {
            const bf16* xb = (const bf16*)X;
#pragma unroll
            for (int t = 0; t < 4; ++t) {
                int g8 = wave * 4 + t;
                int r = g8 * 8 + (lane >> 3);
                int gr = row0 + r; if (gr >= NNODES) gr = NNODES - 1;
                int ck = (lane & 7) ^ (r & 7);
                load_lds16(xb + (size_t)gr * DFEAT + k0 + ck * 8, Asb + g8 * 8 * 64);
            }
        } else {
            const float* xf = (const float*)X;
            for (int i = tid; i < 128 * 8; i += 256) {
                int r = i >> 3, p = i & 7;
                int gr = row0 + r; if (gr >= NNODES) gr = NNODES - 1;
                int ck = p ^ (r & 7);
                const float* src = xf + (size_t)gr * DFEAT + k0 + ck * 8;
#pragma unroll
                for (int e = 0; e < 8; ++e)
                    Asb[r * 64 + p * 8 + e] = __float2bfloat16(src[e]);
            }
        }
#pragma unroll
        for (int t = 0; t < 4; ++t) {
            int g8 = wave * 4 + t;
            int cl = g8 * 8 + (lane >> 3);
            int ck = (lane & 7) ^ (cl & 7);
            load_lds16(W1T + (size_t)(gc0 + cl) * DFEAT + k0 + ck * 8, Bsb + g8 * 8 * 64);
        }
    };

    // prologue: stage first K-tile, drain, then pipeline
    stageAB(0, As[0], Bs[0]);
    __syncthreads();
    int cur = 0;

    for (int k0 = 0; k0 < DFEAT; k0 += 64) {
        if (k0 + 64 < DFEAT) stageAB(k0 + 64, As[cur ^ 1], Bs[cur ^ 1]);
        const bf16* Ac = As[cur];
        const bf16* Bc = Bs[cur];
#pragma unroll
        for (int ki = 0; ki < 2; ++ki) {
            const int cc = ki * 4 + fk;
            short8 a[2], b8[8];
#pragma unroll
            for (int i = 0; i < 2; i++) {
                int r = rb + i * 16 + frow;
                a[i] = *(const short8*)&Ac[r * 64 + (cc ^ (r & 7)) * 8];
            }
#pragma unroll
            for (int j = 0; j < 8; j++) {
                int cl = j * 16 + frow;
                b8[j] = *(const short8*)&Bc[cl * 64 + (cc ^ (cl & 7)) * 8];
            }
#pragma unroll
            for (int i = 0; i < 2; i++)
#pragma unroll
                for (int j = 0; j < 8; j++)
                    acc[i][j] = __builtin_amdgcn_mfma_f32_16x16x32_bf16(a[i], b8[j], acc[i][j], 0, 0, 0);
        }
        __syncthreads();   // vmcnt(0)+lgkmcnt(0)+barrier: next buffer ready
        cur ^= 1;
    }

    const int ccol = gc0 - c0;
#pragma unroll
    for (int i = 0; i < 2; i++) {
#pragma unroll
        for (int r = 0; r < 4; r++) {
            int grow = row0 + rb + i * 16 + (lane >> 4) * 4 + r;
            if (grow < NNODES) {
#pragma unroll
                for (int j = 0; j < 8; j++)
                    h1c[(size_t)grow * C + ccol + j * 16 + (lane & 15)] =
                        __float2bfloat16(acc[i][j][r]);
            }
        }
    }
}

// ---------------- legacy GEMM1 (C==64 fallback) ----------------
__global__ __launch_bounds__(256) void k_gemm1_mfma(
    const void* __restrict__ X, const bf16* __restrict__ W1T,
    bf16* __restrict__ h1c, int c0, int C, const int* __restrict__ flags) {
    __shared__ bf16 As[128 * 64];
    __shared__ bf16 Bs[64 * 64];
    const int tid = threadIdx.x;
    const int wave = tid >> 6, lane = tid & 63;
    const int row0 = blockIdx.x * 128;
    const int gc0 = c0 + blockIdx.y * 64;
    const int isb = flags[0];
    float4v acc[2][4];
#pragma unroll
    for (int i = 0; i < 2; i++)
#pragma unroll
        for (int j = 0; j < 4; j++) acc[i][j] = (float4v){0.f, 0.f, 0.f, 0.f};
    const int rbase = wave * 32;
    const int fl_row = lane & 15;
    const int fl_k8 = (lane >> 4) * 8;
    for (int k0 = 0; k0 < DFEAT; k0 += 64) {
        __syncthreads();
        if (isb) {
            const bf16* xb = (const bf16*)X;
#pragma unroll
            for (int i = 0; i < 4; ++i) {
                int r = i * 32 + wave * 8;
                int gr = row0 + r + (lane >> 3);
                if (gr >= NNODES) gr = NNODES - 1;
                load_lds16(xb + (size_t)gr * DFEAT + k0 + (lane & 7) * 8, &As[r * 64]);
            }
        } else {
            const float* xf = (const float*)X;
            for (int i = tid; i < 128 * 64; i += 256) {
                int r = i >> 6, c = i & 63;
                int gr = row0 + r;
                if (gr >= NNODES) gr = NNODES - 1;
                As[i] = __float2bfloat16(xf[(size_t)gr * DFEAT + k0 + c]);
            }
        }
#pragma unroll
        for (int i = 0; i < 2; ++i) {
            int r = i * 32 + wave * 8;
            int gn = gc0 + r + (lane >> 3);
            load_lds16(W1T + (size_t)gn * DFEAT + k0 + (lane & 7) * 8, &Bs[r * 64]);
        }
        __syncthreads();
#pragma unroll
        for (int ki = 0; ki < 64; ki += 32) {
            short8 a[2], b[4];
#pragma unroll
            for (int i = 0; i < 2; i++)
                a[i] = *(const short8*)&As[(rbase + i * 16 + fl_row) * 64 + ki + fl_k8];
#pragma unroll
            for (int j = 0; j < 4; j++)
                b[j] = *(const short8*)&Bs[(j * 16 + fl_row) * 64 + ki + fl_k8];
#pragma unroll
            for (int i = 0; i < 2; i++)
#pragma unroll
                for (int j = 0; j < 4; j++)
                    acc[i][j] = __builtin_amdgcn_mfma_f32_16x16x32_bf16(a[i], b[j], acc[i][j], 0, 0, 0);
        }
    }
    const int ccol = blockIdx.y * 64;
#pragma unroll
    for (int i = 0; i < 2; i++) {
#pragma unroll
        for (int r = 0; r < 4; r++) {
            int grow = row0 + rbase + i * 16 + (lane >> 4) * 4 + r;
            if (grow < NNODES) {
#pragma unroll
                for (int j = 0; j < 4; j++)
                    h1c[(size_t)grow * C + ccol + j * 16 + (lane & 15)] =
                        __float2bfloat16(acc[i][j][r]);
            }
        }
    }
}

// ---------------- layer1 aggregation, C=512: one wave per node, uint4 loads ----
__global__ __launch_bounds__(256) void k_agg1_512(const bf16* __restrict__ h1c,
                                                  const int* __restrict__ rowptr,
                                                  const int* __restrict__ csr_src,
                                                  const float* __restrict__ dinv,
                                                  const float* __restrict__ b1c,
                                                  bf16* __restrict__ a1c) {
    int v = blockIdx.x * 4 + (threadIdx.x >> 6);
    int lane = threadIdx.x & 63;
    if (v >= NNODES) return;
    int d8 = lane * 8;
    float dv = dinv[v];
    float s2 = dv * dv;
    uint4 w = *(const uint4*)(h1c + (size_t)v * 512 + d8);
    float a0 = s2 * bfbits_lo(w.x), a1 = s2 * bfbits_hi(w.x);
    float a2 = s2 * bfbits_lo(w.y), a3 = s2 * bfbits_hi(w.y);
    float a4 = s2 * bfbits_lo(w.z), a5 = s2 * bfbits_hi(w.z);
    float a6 = s2 * bfbits_lo(w.w), a7 = s2 * bfbits_hi(w.w);
    int pend = rowptr[v + 1];
    for (int p = rowptr[v]; p < pend; ++p) {
        int u = csr_src[p];
        float nw = dinv[u] * dv;
        uint4 q = *(const uint4*)(h1c + (size_t)u * 512 + d8);
        a0 += nw * bfbits_lo(q.x); a1 += nw * bfbits_hi(q.x);
        a2 += nw * bfbits_lo(q.y); a3 += nw * bfbits_hi(q.y);
        a4 += nw * bfbits_lo(q.z); a5 += nw * bfbits_hi(q.z);
        a6 += nw * bfbits_lo(q.w); a7 += nw * bfbits_hi(q.w);
    }
    const float* bb = b1c + d8;
    a0 += bb[0]; a1 += bb[1]; a2 += bb[2]; a3 += bb[3];
    a4 += bb[4]; a5 += bb[5]; a6 += bb[6]; a7 += bb[7];
    bf16 o[8];
    o[0] = __float2bfloat16(a0 > 0.f ? a0 : 0.f);
    o[1] = __float2bfloat16(a1 > 0.f ? a1 : 0.f);
    o[2] = __float2bfloat16(a2 > 0.f ? a2 : 0.f);
    o[3] = __float2bfloat16(a3 > 0.f ? a3 : 0.f);
    o[4] = __float2bfloat16(a4 > 0.f ? a4 : 0.f);
    o[5] = __float2bfloat16(a5 > 0.f ? a5 : 0.f);
    o[6] = __float2bfloat16(a6 > 0.f ? a6 : 0.f);
    o[7] = __float2bfloat16(a7 > 0.f ? a7 : 0.f);
    *(uint4*)(a1c + (size_t)v * 512 + d8) = *(uint4*)o;
}

// ---------------- layer1 aggregation, generic ----------------
__global__ __launch_bounds__(256) void k_agg1(const bf16* __restrict__ h1c,
                                              const int* __restrict__ rowptr,
                                              const int* __restrict__ csr_src,
                                              const float* __restrict__ dinv,
                                              const float* __restrict__ b1c, int c0, int C,
                                              bf16* __restrict__ a1c) {
    const int tshift = (C == 512) ? 7 : (C == 256) ? 6 : (C == 128) ? 5 : 4;
    long long gt = (long long)blockIdx.x * 256 + threadIdx.x;
    int v = (int)(gt >> tshift);
    int d4 = (int)((gt & ((1 << tshift) - 1)) << 2);
    if (v >= NNODES) return;
    float dv = dinv[v];
    uint2 w = *(const uint2*)(h1c + (size_t)v * C + d4);
    float s2 = dv * dv;
    float a0 = s2 * bfbits_lo(w.x), a1 = s2 * bfbits_hi(w.x);
    float a2 = s2 * bfbits_lo(w.y), a3 = s2 * bfbits_hi(w.y);
    int pend = rowptr[v + 1];
    for (int p = rowptr[v]; p < pend; ++p) {
        int u = csr_src[p];
        float nw = dinv[u] * dv;
        uint2 q = *(const uint2*)(h1c + (size_t)u * C + d4);
        a0 += nw * bfbits_lo(q.x); a1 += nw * bfbits_hi(q.x);
        a2 += nw * bfbits_lo(q.y); a3 += nw * bfbits_hi(q.y);
    }
    const float* bb = b1c + c0 + d4;
    a0 += bb[0]; a1 += bb[1]; a2 += bb[2]; a3 += bb[3];
    bf16 o[4];
    o[0] = __float2bfloat16(a0 > 0.f ? a0 : 0.f);
    o[1] = __float2bfloat16(a1 > 0.f ? a1 : 0.f);
    o[2] = __float2bfloat16(a2 > 0.f ? a2 : 0.f);
    o[3] = __float2bfloat16(a3 > 0.f ? a3 : 0.f);
    *(uint2*)(a1c + (size_t)v * C + d4) = *(uint2*)o;
}

// ---------------- GEMM2 v2: 2-phase double-buffer + XOR-swizzled LDS ----------
__global__ __launch_bounds__(256, 3) void k_gemm2_v2(
    const bf16* __restrict__ A, int C, const bf16* __restrict__ W2T, int kg0,
    float* __restrict__ h2, int accum) {
    __shared__ bf16 As[2][128 * 64];   // 2 x 16 KiB
    __shared__ bf16 Bs[2][64 * 64];    // 2 x  8 KiB  -> 48 KiB, 3 blocks/CU
    const int tid = threadIdx.x;
    const int wave = tid >> 6, lane = tid & 63;
    const int row0 = blockIdx.x * 128;
    float4v acc[2][4];
#pragma unroll
    for (int i = 0; i < 2; i++)
#pragma unroll
        for (int j = 0; j < 4; j++) acc[i][j] = (float4v){0.f, 0.f, 0.f, 0.f};
    const int rb = wave * 32;
    const int frow = lane & 15;
    const int fk = lane >> 4;

    auto stage2 = [&](int kk, bf16* Asb, bf16* Bsb) {
#pragma unroll
        for (int t = 0; t < 4; ++t) {
            int g8 = wave * 4 + t;
            int r = g8 * 8 + (lane >> 3);
            int gr = row0 + r; if (gr >= NNODES) gr = NNODES - 1;
            int ck = (lane & 7) ^ (r & 7);
            load_lds16(A + (size_t)gr * C + kk + ck * 8, Asb + g8 * 8 * 64);
        }
#pragma unroll
        for (int t = 0; t < 2; ++t) {
            int g8 = wave * 2 + t;
            int cl = g8 * 8 + (lane >> 3);
            int ck = (lane & 7) ^ (cl & 7);
            load_lds16(W2T + (size_t)cl * HID + kg0 + kk + ck * 8, Bsb + g8 * 8 * 64);
        }
    };

    stage2(0, As[0], Bs[0]);
    __syncthreads();
    int cur = 0;

    for (int kk = 0; kk < C; kk += 64) {
        if (kk + 64 < C) stage2(kk + 64, As[cur ^ 1], Bs[cur ^ 1]);
        const bf16* Ac = As[cur];
        const bf16* Bc = Bs[cur];
#pragma unroll
        for (int ki = 0; ki < 2; ++ki) {
            const int cc = ki * 4 + fk;
            short8 a[2], b8[4];
#pragma unroll
            for (int i = 0; i < 2; i++) {
                int r = rb + i * 16 + frow;
                a[i] = *(const short8*)&Ac[r * 64 + (cc ^ (r & 7)) * 8];
            }
#pragma unroll
            for (int j = 0; j < 4; j++) {
                int cl = j * 16 + frow;
                b8[j] = *(const short8*)&Bc[cl * 64 + (cc ^ (cl & 7)) * 8];
            }
#pragma unroll
            for (int i = 0; i < 2; i++)
#pragma unroll
                for (int j = 0; j < 4; j++)
                    acc[i][j] = __builtin_amdgcn_mfma_f32_16x16x32_bf16(a[i], b8[j], acc[i][j], 0, 0, 0);
        }
        __syncthreads();
        cur ^= 1;
    }
#pragma unroll
    for (int i = 0; i < 2; i++) {
#pragma unroll
        for (int r = 0; r < 4; r++) {
            int grow = row0 + rb + i * 16 + (lane >> 4) * 4 + r;
            if (grow < NNODES) {
#pragma unroll
                for (int j = 0; j < 4; j++) {
                    int col = j * 16 + (lane & 15);
                    if (col < NCLS) {
                        size_t o = (size_t)grow * NCLS + col;
                        h2[o] = accum ? h2[o] + acc[i][j][r] : acc[i][j][r];
                    }
                }
            }
        }
    }
}

// ---------------- layer2 aggregation + bias -> out ----------------
__global__ __launch_bounds__(256) void k_agg2(const float* __restrict__ h2,
                                              const int* __restrict__ rowptr,
                                              const int* __restrict__ csr_src,
                                              const float* __restrict__ dinv,
                                              const float* __restrict__ b2c,
                                              void* out, const int* flags) {
    int v = blockIdx.x * 4 + (threadIdx.x >> 6);
    int d = threadIdx.x & 63;
    if (v >= NNODES || d >= NCLS) return;
    float dv = dinv[v];
    float acc = dv * dv * h2[(size_t)v * NCLS + d];
    int pend = rowptr[v + 1];
    for (int p = rowptr[v]; p < pend; ++p) {
        int u = csr_src[p];
        acc += dinv[u] * dv * h2[(size_t)u * NCLS + d];
    }
    acc += b2c[d];
    size_t o = (size_t)v * NCLS + d;
    if (flags[0]) ((bf16*)out)[o] = __float2bfloat16(acc);
    else          ((float*)out)[o] = acc;
}

extern "C" void kernel_launch(void* const* d_in, const int* in_sizes, int n_in,
                              void* d_out, int out_size, void* d_ws, size_t ws_size,
                              hipStream_t stream) {
    const void* x  = d_in[0];
    const void* ei = d_in[1];
    const void* W1 = d_in[2];
    const void* b1 = d_in[3];
    const void* W2 = d_in[4];
    const void* b2 = d_in[5];

    char* base = (char*)d_ws;
    auto alloc = [&](size_t bytes) -> char* {
        char* p = base;
        base += (bytes + 255) & ~(size_t)255;
        return p;
    };
    int*   flags  = (int*)alloc(64);
    int*   cnt    = (int*)alloc(sizeof(int) * NNODES);
    int*   part   = (int*)alloc(sizeof(int) * 256);
    int*   rowptr = (int*)alloc(sizeof(int) * (NNODES + 1));
    int*   cursor = (int*)alloc(sizeof(int) * NNODES);
    int*   csr    = (int*)alloc(sizeof(int) * NEDGES);
    float* dinv   = (float*)alloc(sizeof(float) * NNODES);
    bf16*  W1T    = (bf16*)alloc(sizeof(bf16) * DFEAT * HID);
    float* b1c    = (float*)alloc(sizeof(float) * HID);
    bf16*  W2T    = (bf16*)alloc(sizeof(bf16) * 64 * HID);
    float* b2c    = (float*)alloc(sizeof(float) * 64);
    float* h2     = (float*)alloc(sizeof(float) * (size_t)NNODES * NCLS);

    size_t used = (size_t)(base - (char*)d_ws);
    size_t rem = (ws_size > used) ? ws_size - used : 0;
    int C = 64;
    if (rem >= (size_t)200000 * 512 + 1024) C = 512;
    else if (rem >= (size_t)200000 * 256 + 1024) C = 256;
    else if (rem >= (size_t)200000 * 128 + 1024) C = 128;
    bf16* h1c = (bf16*)alloc(sizeof(bf16) * (size_t)NNODES * C);
    bf16* a1c = (bf16*)alloc(sizeof(bf16) * (size_t)NNODES * C);

    k_detect<<<1, 64, 0, stream>>>(x, ei, flags);
    k_zero32<<<(NNODES + 255) / 256, 256, 0, stream>>>((unsigned int*)cnt, NNODES);

    k_cvt_w1t<<<(DFEAT * HID + 255) / 256, 256, 0, stream>>>(W1, W1T, flags);
    k_cvt<<<(HID + 255) / 256, 256, 0, stream>>>(b1, b1c, HID, flags);
    k_cvt_w2t<<<(64 * HID + 255) / 256, 256, 0, stream>>>(W2, W2T, flags);
    k_cvt<<<1, 64, 0, stream>>>(b2, b2c, NCLS, flags);

    k_count<<<(NEDGES + 255) / 256, 256, 0, stream>>>(ei, cnt, flags);
    k_dinv<<<(NNODES + 255) / 256, 256, 0, stream>>>(cnt, dinv);
    const int nsb = (NNODES + 255) / 256;  // 196
    k_scan_part<<<nsb, 256, 0, stream>>>(cnt, part);
    k_scan_off<<<1, 256, 0, stream>>>(part, nsb);
    k_scan_fin<<<nsb, 256, 0, stream>>>(cnt, part, rowptr, cursor);
    k_fill<<<(NEDGES + 255) / 256, 256, 0, stream>>>(ei, cursor, csr, flags);

    const int rowblocks = (NNODES + 127) / 128;  // 391
    const int rows_per_xcd = (rowblocks + 7) / 8;  // 49
    int chunk_i = 0;
    for (int c0 = 0; c0 < HID; c0 += C, ++chunk_i) {
        if (C >= 128) {
            int col_tiles = C / 128;
            int nblk = 8 * rows_per_xcd * col_tiles;
            k_gemm1_v4<<<nblk, 256, 0, stream>>>(x, W1T, h1c, c0, C, flags,
                                                 col_tiles, rows_per_xcd, rowblocks);
        } else {
            dim3 g1(rowblocks, 1);
            k_gemm1_mfma<<<g1, 256, 0, stream>>>(x, W1T, h1c, c0, C, flags);
        }
        if (C == 512) {
            k_agg1_512<<<(NNODES + 3) / 4, 256, 0, stream>>>(h1c, rowptr, csr, dinv, b1c, a1c);
        } else {
            size_t nthr = (size_t)NNODES * (C / 4);
            k_agg1<<<(int)((nthr + 255) / 256), 256, 0, stream>>>(h1c, rowptr, csr, dinv, b1c, c0, C, a1c);
        }
        k_gemm2_v2<<<rowblocks, 256, 0, stream>>>(a1c, C, W2T, c0, h2, chunk_i > 0 ? 1 : 0);
    }

    k_agg2<<<(NNODES + 3) / 4, 256, 0, stream>>>(h2, rowptr, csr, dinv, b2c, d_out, flags);
}

// Round 2
// 366.486 us; speedup vs baseline: 1.0117x; 1.0117x over previous
//
#include <hip/hip_runtime.h>
#include <hip/hip_bf16.h>

#define NNODES 50000
#define NEDGES 150000
#define DFEAT  512
#define HID    512
#define NCLS   47

typedef __hip_bfloat16 bf16;
typedef __attribute__((ext_vector_type(8))) short short8;
typedef __attribute__((ext_vector_type(4))) float float4v;

typedef const __attribute__((address_space(1))) unsigned int* gas_t;
typedef __attribute__((address_space(3))) unsigned int* las_t;
__device__ __forceinline__ void load_lds16(const void* g, void* l) {
    __builtin_amdgcn_global_load_lds((gas_t)g, (las_t)l, 16, 0, 0);
}

__device__ __forceinline__ float bfbits_lo(unsigned int w) {
    return __uint_as_float((w & 0xFFFFu) << 16);
}
__device__ __forceinline__ float bfbits_hi(unsigned int w) {
    return __uint_as_float(w & 0xFFFF0000u);
}

// ---------------- dtype detection (1 block, 64 threads) ----------------
__global__ void k_detect(const void* x, const void* ei, int* flags) {
    __shared__ int scnt[64], sor[64];
    int t = threadIdx.x;
    const unsigned short* xs = (const unsigned short*)x;
    int c = 0;
    for (int i = t; i < 256; i += 64) {
        unsigned int e = (xs[2 * i] >> 7) & 0xFF;
        c += (e >= 117 && e <= 130) ? 1 : 0;
    }
    const int* w = (const int*)ei;
    int o = 0;
    for (int i = 2 * t + 1; i < 512; i += 128) o |= w[i];
    scnt[t] = c; sor[t] = o;
    __syncthreads();
    if (t == 0) {
        int C = 0, O = 0;
        for (int i = 0; i < 64; i++) { C += scnt[i]; O |= sor[i]; }
        flags[0] = (C > 128) ? 1 : 0;
        flags[1] = (O == 0) ? 1 : 0;
    }
}

__device__ __forceinline__ int eidx(const void* ei, int half, int e, int is64) {
    if (is64) return (int)((const long long*)ei)[(size_t)half * NEDGES + e];
    return ((const int*)ei)[half * NEDGES + e];
}

// ---------------- utility ----------------
__global__ void k_zero32(unsigned int* p, size_t n) {
    size_t i = (size_t)blockIdx.x * blockDim.x + threadIdx.x;
    if (i < n) p[i] = 0u;
}

__global__ void k_cvt(const void* src, float* dst, int n, const int* flags) {
    int i = blockIdx.x * blockDim.x + threadIdx.x;
    if (i >= n) return;
    dst[i] = flags[0] ? __bfloat162float(((const bf16*)src)[i]) : ((const float*)src)[i];
}

// W1 [K=512][N=512] -> W1T bf16 [N][K]
__global__ void k_cvt_w1t(const void* W1, bf16* W1T, const int* flags) {
    int i = blockIdx.x * blockDim.x + threadIdx.x;
    if (i >= DFEAT * HID) return;
    int k = i / HID, n = i % HID;
    float v = flags[0] ? __bfloat162float(((const bf16*)W1)[i]) : ((const float*)W1)[i];
    W1T[(size_t)n * DFEAT + k] = __float2bfloat16(v);
}

// W2 [K=512][N=47] -> W2T bf16 [64][512] zero-padded
__global__ void k_cvt_w2t(const void* W2, bf16* W2T, const int* flags) {
    int i = blockIdx.x * blockDim.x + threadIdx.x;
    if (i >= 64 * HID) return;
    int n = i / HID, k = i % HID;
    float v = 0.0f;
    if (n < NCLS) {
        size_t idx = (size_t)k * NCLS + n;
        v = flags[0] ? __bfloat162float(((const bf16*)W2)[idx]) : ((const float*)W2)[idx];
    }
    W2T[(size_t)n * HID + k] = __float2bfloat16(v);
}

// ---------------- graph structure ----------------
__global__ void k_count(const void* ei, int* cnt, const int* flags) {
    int e = blockIdx.x * blockDim.x + threadIdx.x;
    if (e >= NEDGES) return;
    atomicAdd(&cnt[eidx(ei, 1, e, flags[1])], 1);
}

__global__ void k_dinv(const int* cnt, float* dinv) {
    int i = blockIdx.x * blockDim.x + threadIdx.x;
    if (i < NNODES) dinv[i] = rsqrtf(1.0f + (float)cnt[i]);
}

__global__ __launch_bounds__(256) void k_scan_part(const int* cnt, int* part) {
    __shared__ int s[256];
    int i = blockIdx.x * 256 + threadIdx.x;
    s[threadIdx.x] = (i < NNODES) ? cnt[i] : 0;
    __syncthreads();
    for (int off = 128; off > 0; off >>= 1) {
        if (threadIdx.x < off) s[threadIdx.x] += s[threadIdx.x + off];
        __syncthreads();
    }
    if (threadIdx.x == 0) part[blockIdx.x] = s[0];
}

__global__ __launch_bounds__(256) void k_scan_off(int* part, int n) {
    __shared__ int s[256];
    int v = (threadIdx.x < n) ? part[threadIdx.x] : 0;
    s[threadIdx.x] = v;
    __syncthreads();
    for (int off = 1; off < 256; off <<= 1) {
        int t = (threadIdx.x >= off) ? s[threadIdx.x - off] : 0;
        __syncthreads();
        s[threadIdx.x] += t;
        __syncthreads();
    }
    if (threadIdx.x < n) part[threadIdx.x] = s[threadIdx.x] - v;
}

__global__ __launch_bounds__(256) void k_scan_fin(const int* cnt, const int* part,
                                                  int* rowptr, int* cursor) {
    __shared__ int s[256];
    int i = blockIdx.x * 256 + threadIdx.x;
    int v = (i < NNODES) ? cnt[i] : 0;
    s[threadIdx.x] = v;
    __syncthreads();
    for (int off = 1; off < 256; off <<= 1) {
        int t = (threadIdx.x >= off) ? s[threadIdx.x - off] : 0;
        __syncthreads();
        s[threadIdx.x] += t;
        __syncthreads();
    }
    int incl = s[threadIdx.x] + part[blockIdx.x];
    if (i < NNODES) {
        rowptr[i + 1] = incl;
        cursor[i] = incl - v;
    }
    if (i == 0) rowptr[0] = 0;
}

__global__ void k_fill(const void* ei, int* cursor, int* csr_src, const int* flags) {
    int e = blockIdx.x * blockDim.x + threadIdx.x;
    if (e >= NEDGES) return;
    int is64 = flags[1];
    int v = eidx(ei, 1, e, is64);
    int u = eidx(ei, 0, e, is64);
    int pos = atomicAdd(&cursor[v], 1);
    csr_src[pos] = u;
}

// ---------------- GEMM1 v5: 128x128, XOR-swizzled LDS, XCD-aware remap,
// TRUE 2-phase pipeline: double-buffered LDS + counted s_waitcnt vmcnt(8) +
// raw s_barrier, so the prefetch for tile k+1 stays IN FLIGHT across the
// barriers (T3+T4). __syncthreads() would drain vmcnt(0) and kill the
// overlap (the Round-1 regression).
// Safety: vmcnt retires oldest-first, so vmcnt(8) == "my 8 current-tile
// loads have landed"; s_barrier then makes the whole tile visible. The
// post-compute barrier protects buf[cur] from next-iter overwrite: every
// ds_read of buf[cur] is consumed by an MFMA (compiler lgkmcnt) before it.
__global__ __launch_bounds__(256, 2) void k_gemm1_v5(
    const void* __restrict__ X, const bf16* __restrict__ W1T,
    bf16* __restrict__ h1c, int c0, int C, const int* __restrict__ flags,
    int col_tiles, int rows_per_xcd, int n_row_tiles) {
    const int b = blockIdx.x;
    const int xcd = b & 7;
    const int s = b >> 3;
    const int col_t = s % col_tiles;
    const int lr = s / col_tiles;
    const int row_t = xcd * rows_per_xcd + lr;
    if (row_t >= n_row_tiles) return;

    __shared__ bf16 As[2][128 * 64];   // 2 x 16 KiB
    __shared__ bf16 Bs[2][128 * 64];   // 2 x 16 KiB  -> 64 KiB total
    const int tid = threadIdx.x;
    const int wave = tid >> 6, lane = tid & 63;
    const int row0 = row_t * 128;
    const int gc0 = c0 + col_t * 128;
    const int isb = flags[0];

    float4v acc[2][8];
#pragma unroll
    for (int i = 0; i < 2; i++)
#pragma unroll
        for (int j = 0; j < 8; j++) acc[i][j] = (float4v){0.f, 0.f, 0.f, 0.f};

    const int rb = wave * 32;
    const int frow = lane & 15;
    const int fk = lane >> 4;

    // bf16 staging: 4 A-loads + 4 B-loads per lane = 8 global_load_lds
    auto stageAB_b = [&](int k0, bf16* Asb, bf16* Bsb) {
        const bf16* xb = (const bf16*)X;
#pragma unroll
        for (int t = 0; t < 4; ++t) {
            int g8 = wave * 4 + t;
            int r = g8 * 8 + (lane >> 3);
            int gr = row0 + r; if (gr >= NNODES) gr = NNODES - 1;
            int ck = (lane & 7) ^ (r & 7);
            load_lds16(xb + (size_t)gr * DFEAT + k0 + ck * 8, Asb + g8 * 8 * 64);
        }
#pragma unroll
        for (int t = 0; t < 4; ++t) {
            int g8 = wave * 4 + t;
            int cl = g8 * 8 + (lane >> 3);
            int ck = (lane & 7) ^ (cl & 7);
            load_lds16(W1T + (size_t)(gc0 + cl) * DFEAT + k0 + ck * 8, Bsb + g8 * 8 * 64);
        }
    };
    // f32 fallback staging (dead path for bf16 inputs; correctness only)
    auto stageAB_f = [&](int k0, bf16* Asb, bf16* Bsb) {
        const float* xf = (const float*)X;
        for (int i = tid; i < 128 * 8; i += 256) {
            int r = i >> 3, p = i & 7;
            int gr = row0 + r; if (gr >= NNODES) gr = NNODES - 1;
            int ck = p ^ (r & 7);
            const float* src = xf + (size_t)gr * DFEAT + k0 + ck * 8;
#pragma unroll
            for (int e = 0; e < 8; ++e)
                Asb[r * 64 + p * 8 + e] = __float2bfloat16(src[e]);
        }
#pragma unroll
        for (int t = 0; t < 4; ++t) {
            int g8 = wave * 4 + t;
            int cl = g8 * 8 + (lane >> 3);
            int ck = (lane & 7) ^ (cl & 7);
            load_lds16(W1T + (size_t)(gc0 + cl) * DFEAT + k0 + ck * 8, Bsb + g8 * 8 * 64);
        }
    };

    auto compute = [&](const bf16* Ac, const bf16* Bc) {
#pragma unroll
        for (int ki = 0; ki < 2; ++ki) {
            const int cc = ki * 4 + fk;
            short8 a[2], b8[8];
#pragma unroll
            for (int i = 0; i < 2; i++) {
                int r = rb + i * 16 + frow;
                a[i] = *(const short8*)&Ac[r * 64 + (cc ^ (r & 7)) * 8];
            }
#pragma unroll
            for (int j = 0; j < 8; j++) {
                int cl = j * 16 + frow;
                b8[j] = *(const short8*)&Bc[cl * 64 + (cc ^ (cl & 7)) * 8];
            }
#pragma unroll
            for (int i = 0; i < 2; i++)
#pragma unroll
                for (int j = 0; j < 8; j++)
                    acc[i][j] = __builtin_amdgcn_mfma_f32_16x16x32_bf16(a[i], b8[j], acc[i][j], 0, 0, 0);
        }
    };

    if (isb) {
        // ---- pipelined bf16 path: counted vmcnt, loads span barriers ----
        stageAB_b(0, As[0], Bs[0]);
        asm volatile("s_waitcnt vmcnt(0)" ::: "memory");
        __builtin_amdgcn_s_barrier();
        int cur = 0;
#pragma unroll
        for (int k0 = 0; k0 < DFEAT; k0 += 64) {
            if (k0 + 64 < DFEAT) {
                stageAB_b(k0 + 64, As[cur ^ 1], Bs[cur ^ 1]);
                asm volatile("s_waitcnt vmcnt(8)" ::: "memory");  // cur tile landed; prefetch in flight
            } else {
                asm volatile("s_waitcnt vmcnt(0)" ::: "memory");
            }
            __builtin_amdgcn_s_barrier();
            compute(As[cur], Bs[cur]);
            __builtin_amdgcn_s_barrier();   // all reads of buf[cur] done before overwrite
            cur ^= 1;
        }
    } else {
        // ---- f32 fallback: simple dbuf with full syncthreads ----
        stageAB_f(0, As[0], Bs[0]);
        __syncthreads();
        int cur = 0;
        for (int k0 = 0; k0 < DFEAT; k0 += 64) {
            if (k0 + 64 < DFEAT) stageAB_f(k0 + 64, As[cur ^ 1], Bs[cur ^ 1]);
            compute(As[cur], Bs[cur]);
            __syncthreads();
            cur ^= 1;
        }
    }

    const int ccol = gc0 - c0;
#pragma unroll
    for (int i = 0; i < 2; i++) {
#pragma unroll
        for (int r = 0; r < 4; r++) {
            int grow = row0 + rb + i * 16 + (lane >> 4) * 4 + r;
            if (grow < NNODES) {
#pragma unroll
                for (int j = 0; j < 8; j++)
                    h1c[(size_t)grow * C + ccol + j * 16 + (lane & 15)] =
                        __float2bfloat16(acc[i][j][r]);
            }
        }
    }
}

// ---------------- legacy GEMM1 (C==64 fallback) ----------------
__global__ __launch_bounds__(256) void k_gemm1_mfma(
    const void* __restrict__ X, const bf16* __restrict__ W1T,
    bf16* __restrict__ h1c, int c0, int C, const int* __restrict__ flags) {
    __shared__ bf16 As[128 * 64];
    __shared__ bf16 Bs[64 * 64];
    const int tid = threadIdx.x;
    const int wave = tid >> 6, lane = tid & 63;
    const int row0 = blockIdx.x * 128;
    const int gc0 = c0 + blockIdx.y * 64;
    const int isb = flags[0];
    float4v acc[2][4];
#pragma unroll
    for (int i = 0; i < 2; i++)
#pragma unroll
        for (int j = 0; j < 4; j++) acc[i][j] = (float4v){0.f, 0.f, 0.f, 0.f};
    const int rbase = wave * 32;
    const int fl_row = lane & 15;
    const int fl_k8 = (lane >> 4) * 8;
    for (int k0 = 0; k0 < DFEAT; k0 += 64) {
        __syncthreads();
        if (isb) {
            const bf16* xb = (const bf16*)X;
#pragma unroll
            for (int i = 0; i < 4; ++i) {
                int r = i * 32 + wave * 8;
                int gr = row0 + r + (lane >> 3);
                if (gr >= NNODES) gr = NNODES - 1;
                load_lds16(xb + (size_t)gr * DFEAT + k0 + (lane & 7) * 8, &As[r * 64]);
            }
        } else {
            const float* xf = (const float*)X;
            for (int i = tid; i < 128 * 64; i += 256) {
                int r = i >> 6, c = i & 63;
                int gr = row0 + r;
                if (gr >= NNODES) gr = NNODES - 1;
                As[i] = __float2bfloat16(xf[(size_t)gr * DFEAT + k0 + c]);
            }
        }
#pragma unroll
        for (int i = 0; i < 2; ++i) {
            int r = i * 32 + wave * 8;
            int gn = gc0 + r + (lane >> 3);
            load_lds16(W1T + (size_t)gn * DFEAT + k0 + (lane & 7) * 8, &Bs[r * 64]);
        }
        __syncthreads();
#pragma unroll
        for (int ki = 0; ki < 64; ki += 32) {
            short8 a[2], b[4];
#pragma unroll
            for (int i = 0; i < 2; i++)
                a[i] = *(const short8*)&As[(rbase + i * 16 + fl_row) * 64 + ki + fl_k8];
#pragma unroll
            for (int j = 0; j < 4; j++)
                b[j] = *(const short8*)&Bs[(j * 16 + fl_row) * 64 + ki + fl_k8];
#pragma unroll
            for (int i = 0; i < 2; i++)
#pragma unroll
                for (int j = 0; j < 4; j++)
                    acc[i][j] = __builtin_amdgcn_mfma_f32_16x16x32_bf16(a[i], b[j], acc[i][j], 0, 0, 0);
        }
    }
    const int ccol = blockIdx.y * 64;
#pragma unroll
    for (int i = 0; i < 2; i++) {
#pragma unroll
        for (int r = 0; r < 4; r++) {
            int grow = row0 + rbase + i * 16 + (lane >> 4) * 4 + r;
            if (grow < NNODES) {
#pragma unroll
                for (int j = 0; j < 4; j++)
                    h1c[(size_t)grow * C + ccol + j * 16 + (lane & 15)] =
                        __float2bfloat16(acc[i][j][r]);
            }
        }
    }
}

// ---------------- layer1 aggregation, C=512: one wave per node, uint4 loads ----
__global__ __launch_bounds__(256) void k_agg1_512(const bf16* __restrict__ h1c,
                                                  const int* __restrict__ rowptr,
                                                  const int* __restrict__ csr_src,
                                                  const float* __restrict__ dinv,
                                                  const float* __restrict__ b1c,
                                                  bf16* __restrict__ a1c) {
    int v = blockIdx.x * 4 + (threadIdx.x >> 6);
    int lane = threadIdx.x & 63;
    if (v >= NNODES) return;
    int d8 = lane * 8;
    float dv = dinv[v];
    float s2 = dv * dv;
    uint4 w = *(const uint4*)(h1c + (size_t)v * 512 + d8);
    float a0 = s2 * bfbits_lo(w.x), a1 = s2 * bfbits_hi(w.x);
    float a2 = s2 * bfbits_lo(w.y), a3 = s2 * bfbits_hi(w.y);
    float a4 = s2 * bfbits_lo(w.z), a5 = s2 * bfbits_hi(w.z);
    float a6 = s2 * bfbits_lo(w.w), a7 = s2 * bfbits_hi(w.w);
    int pend = rowptr[v + 1];
    for (int p = rowptr[v]; p < pend; ++p) {
        int u = csr_src[p];
        float nw = dinv[u] * dv;
        uint4 q = *(const uint4*)(h1c + (size_t)u * 512 + d8);
        a0 += nw * bfbits_lo(q.x); a1 += nw * bfbits_hi(q.x);
        a2 += nw * bfbits_lo(q.y); a3 += nw * bfbits_hi(q.y);
        a4 += nw * bfbits_lo(q.z); a5 += nw * bfbits_hi(q.z);
        a6 += nw * bfbits_lo(q.w); a7 += nw * bfbits_hi(q.w);
    }
    const float* bb = b1c + d8;
    a0 += bb[0]; a1 += bb[1]; a2 += bb[2]; a3 += bb[3];
    a4 += bb[4]; a5 += bb[5]; a6 += bb[6]; a7 += bb[7];
    bf16 o[8];
    o[0] = __float2bfloat16(a0 > 0.f ? a0 : 0.f);
    o[1] = __float2bfloat16(a1 > 0.f ? a1 : 0.f);
    o[2] = __float2bfloat16(a2 > 0.f ? a2 : 0.f);
    o[3] = __float2bfloat16(a3 > 0.f ? a3 : 0.f);
    o[4] = __float2bfloat16(a4 > 0.f ? a4 : 0.f);
    o[5] = __float2bfloat16(a5 > 0.f ? a5 : 0.f);
    o[6] = __float2bfloat16(a6 > 0.f ? a6 : 0.f);
    o[7] = __float2bfloat16(a7 > 0.f ? a7 : 0.f);
    *(uint4*)(a1c + (size_t)v * 512 + d8) = *(uint4*)o;
}

// ---------------- layer1 aggregation, generic ----------------
__global__ __launch_bounds__(256) void k_agg1(const bf16* __restrict__ h1c,
                                              const int* __restrict__ rowptr,
                                              const int* __restrict__ csr_src,
                                              const float* __restrict__ dinv,
                                              const float* __restrict__ b1c, int c0, int C,
                                              bf16* __restrict__ a1c) {
    const int tshift = (C == 512) ? 7 : (C == 256) ? 6 : (C == 128) ? 5 : 4;
    long long gt = (long long)blockIdx.x * 256 + threadIdx.x;
    int v = (int)(gt >> tshift);
    int d4 = (int)((gt & ((1 << tshift) - 1)) << 2);
    if (v >= NNODES) return;
    float dv = dinv[v];
    uint2 w = *(const uint2*)(h1c + (size_t)v * C + d4);
    float s2 = dv * dv;
    float a0 = s2 * bfbits_lo(w.x), a1 = s2 * bfbits_hi(w.x);
    float a2 = s2 * bfbits_lo(w.y), a3 = s2 * bfbits_hi(w.y);
    int pend = rowptr[v + 1];
    for (int p = rowptr[v]; p < pend; ++p) {
        int u = csr_src[p];
        float nw = dinv[u] * dv;
        uint2 q = *(const uint2*)(h1c + (size_t)u * C + d4);
        a0 += nw * bfbits_lo(q.x); a1 += nw * bfbits_hi(q.x);
        a2 += nw * bfbits_lo(q.y); a3 += nw * bfbits_hi(q.y);
    }
    const float* bb = b1c + c0 + d4;
    a0 += bb[0]; a1 += bb[1]; a2 += bb[2]; a3 += bb[3];
    bf16 o[4];
    o[0] = __float2bfloat16(a0 > 0.f ? a0 : 0.f);
    o[1] = __float2bfloat16(a1 > 0.f ? a1 : 0.f);
    o[2] = __float2bfloat16(a2 > 0.f ? a2 : 0.f);
    o[3] = __float2bfloat16(a3 > 0.f ? a3 : 0.f);
    *(uint2*)(a1c + (size_t)v * C + d4) = *(uint2*)o;
}

// ---------------- GEMM2 v3: counted-vmcnt 2-phase pipeline, 48 KiB LDS ----------
__global__ __launch_bounds__(256, 3) void k_gemm2_v3(
    const bf16* __restrict__ A, int C, const bf16* __restrict__ W2T, int kg0,
    float* __restrict__ h2, int accum) {
    __shared__ bf16 As[2][128 * 64];   // 2 x 16 KiB
    __shared__ bf16 Bs[2][64 * 64];    // 2 x  8 KiB  -> 48 KiB, 3 blocks/CU
    const int tid = threadIdx.x;
    const int wave = tid >> 6, lane = tid & 63;
    const int row0 = blockIdx.x * 128;
    float4v acc[2][4];
#pragma unroll
    for (int i = 0; i < 2; i++)
#pragma unroll
        for (int j = 0; j < 4; j++) acc[i][j] = (float4v){0.f, 0.f, 0.f, 0.f};
    const int rb = wave * 32;
    const int frow = lane & 15;
    const int fk = lane >> 4;

    // 4 A-loads + 2 B-loads per lane = 6 global_load_lds
    auto stage2 = [&](int kk, bf16* Asb, bf16* Bsb) {
#pragma unroll
        for (int t = 0; t < 4; ++t) {
            int g8 = wave * 4 + t;
            int r = g8 * 8 + (lane >> 3);
            int gr = row0 + r; if (gr >= NNODES) gr = NNODES - 1;
            int ck = (lane & 7) ^ (r & 7);
            load_lds16(A + (size_t)gr * C + kk + ck * 8, Asb + g8 * 8 * 64);
        }
#pragma unroll
        for (int t = 0; t < 2; ++t) {
            int g8 = wave * 2 + t;
            int cl = g8 * 8 + (lane >> 3);
            int ck = (lane & 7) ^ (cl & 7);
            load_lds16(W2T + (size_t)cl * HID + kg0 + kk + ck * 8, Bsb + g8 * 8 * 64);
        }
    };

    stage2(0, As[0], Bs[0]);
    asm volatile("s_waitcnt vmcnt(0)" ::: "memory");
    __builtin_amdgcn_s_barrier();
    int cur = 0;
#pragma unroll
    for (int kk = 0; kk < C; kk += 64) {
        if (kk + 64 < C) {
            stage2(kk + 64, As[cur ^ 1], Bs[cur ^ 1]);
            asm volatile("s_waitcnt vmcnt(6)" ::: "memory");
        } else {
            asm volatile("s_waitcnt vmcnt(0)" ::: "memory");
        }
        __builtin_amdgcn_s_barrier();
        const bf16* Ac = As[cur];
        const bf16* Bc = Bs[cur];
#pragma unroll
        for (int ki = 0; ki < 2; ++ki) {
            const int cc = ki * 4 + fk;
            short8 a[2], b8[4];
#pragma unroll
            for (int i = 0; i < 2; i++) {
                int r = rb + i * 16 + frow;
                a[i] = *(const short8*)&Ac[r * 64 + (cc ^ (r & 7)) * 8];
            }
#pragma unroll
            for (int j = 0; j < 4; j++) {
                int cl = j * 16 + frow;
                b8[j] = *(const short8*)&Bc[cl * 64 + (cc ^ (cl & 7)) * 8];
            }
#pragma unroll
            for (int i = 0; i < 2; i++)
#pragma unroll
                for (int j = 0; j < 4; j++)
                    acc[i][j] = __builtin_amdgcn_mfma_f32_16x16x32_bf16(a[i], b8[j], acc[i][j], 0, 0, 0);
        }
        __builtin_amdgcn_s_barrier();
        cur ^= 1;
    }
#pragma unroll
    for (int i = 0; i < 2; i++) {
#pragma unroll
        for (int r = 0; r < 4; r++) {
            int grow = row0 + rb + i * 16 + (lane >> 4) * 4 + r;
            if (grow < NNODES) {
#pragma unroll
                for (int j = 0; j < 4; j++) {
                    int col = j * 16 + (lane & 15);
                    if (col < NCLS) {
                        size_t o = (size_t)grow * NCLS + col;
                        h2[o] = accum ? h2[o] + acc[i][j][r] : acc[i][j][r];
                    }
                }
            }
        }
    }
}

// ---------------- layer2 aggregation + bias -> out ----------------
__global__ __launch_bounds__(256) void k_agg2(const float* __restrict__ h2,
                                              const int* __restrict__ rowptr,
                                              const int* __restrict__ csr_src,
                                              const float* __restrict__ dinv,
                                              const float* __restrict__ b2c,
                                              void* out, const int* flags) {
    int v = blockIdx.x * 4 + (threadIdx.x >> 6);
    int d = threadIdx.x & 63;
    if (v >= NNODES || d >= NCLS) return;
    float dv = dinv[v];
    float acc = dv * dv * h2[(size_t)v * NCLS + d];
    int pend = rowptr[v + 1];
    for (int p = rowptr[v]; p < pend; ++p) {
        int u = csr_src[p];
        acc += dinv[u] * dv * h2[(size_t)u * NCLS + d];
    }
    acc += b2c[d];
    size_t o = (size_t)v * NCLS + d;
    if (flags[0]) ((bf16*)out)[o] = __float2bfloat16(acc);
    else          ((float*)out)[o] = acc;
}

extern "C" void kernel_launch(void* const* d_in, const int* in_sizes, int n_in,
                              void* d_out, int out_size, void* d_ws, size_t ws_size,
                              hipStream_t stream) {
    const void* x  = d_in[0];
    const void* ei = d_in[1];
    const void* W1 = d_in[2];
    const void* b1 = d_in[3];
    const void* W2 = d_in[4];
    const void* b2 = d_in[5];

    char* base = (char*)d_ws;
    auto alloc = [&](size_t bytes) -> char* {
        char* p = base;
        base += (bytes + 255) & ~(size_t)255;
        return p;
    };
    int*   flags  = (int*)alloc(64);
    int*   cnt    = (int*)alloc(sizeof(int) * NNODES);
    int*   part   = (int*)alloc(sizeof(int) * 256);
    int*   rowptr = (int*)alloc(sizeof(int) * (NNODES + 1));
    int*   cursor = (int*)alloc(sizeof(int) * NNODES);
    int*   csr    = (int*)alloc(sizeof(int) * NEDGES);
    float* dinv   = (float*)alloc(sizeof(float) * NNODES);
    bf16*  W1T    = (bf16*)alloc(sizeof(bf16) * DFEAT * HID);
    float* b1c    = (float*)alloc(sizeof(float) * HID);
    bf16*  W2T    = (bf16*)alloc(sizeof(bf16) * 64 * HID);
    float* b2c    = (float*)alloc(sizeof(float) * 64);
    float* h2     = (float*)alloc(sizeof(float) * (size_t)NNODES * NCLS);

    size_t used = (size_t)(base - (char*)d_ws);
    size_t rem = (ws_size > used) ? ws_size - used : 0;
    int C = 64;
    if (rem >= (size_t)200000 * 512 + 1024) C = 512;
    else if (rem >= (size_t)200000 * 256 + 1024) C = 256;
    else if (rem >= (size_t)200000 * 128 + 1024) C = 128;
    bf16* h1c = (bf16*)alloc(sizeof(bf16) * (size_t)NNODES * C);
    bf16* a1c = (bf16*)alloc(sizeof(bf16) * (size_t)NNODES * C);

    k_detect<<<1, 64, 0, stream>>>(x, ei, flags);
    k_zero32<<<(NNODES + 255) / 256, 256, 0, stream>>>((unsigned int*)cnt, NNODES);

    k_cvt_w1t<<<(DFEAT * HID + 255) / 256, 256, 0, stream>>>(W1, W1T, flags);
    k_cvt<<<(HID + 255) / 256, 256, 0, stream>>>(b1, b1c, HID, flags);
    k_cvt_w2t<<<(64 * HID + 255) / 256, 256, 0, stream>>>(W2, W2T, flags);
    k_cvt<<<1, 64, 0, stream>>>(b2, b2c, NCLS, flags);

    k_count<<<(NEDGES + 255) / 256, 256, 0, stream>>>(ei, cnt, flags);
    k_dinv<<<(NNODES + 255) / 256, 256, 0, stream>>>(cnt, dinv);
    const int nsb = (NNODES + 255) / 256;  // 196
    k_scan_part<<<nsb, 256, 0, stream>>>(cnt, part);
    k_scan_off<<<1, 256, 0, stream>>>(part, nsb);
    k_scan_fin<<<nsb, 256, 0, stream>>>(cnt, part, rowptr, cursor);
    k_fill<<<(NEDGES + 255) / 256, 256, 0, stream>>>(ei, cursor, csr, flags);

    const int rowblocks = (NNODES + 127) / 128;  // 391
    const int rows_per_xcd = (rowblocks + 7) / 8;  // 49
    int chunk_i = 0;
    for (int c0 = 0; c0 < HID; c0 += C, ++chunk_i) {
        if (C >= 128) {
            int col_tiles = C / 128;
            int nblk = 8 * rows_per_xcd * col_tiles;
            k_gemm1_v5<<<nblk, 256, 0, stream>>>(x, W1T, h1c, c0, C, flags,
                                                 col_tiles, rows_per_xcd, rowblocks);
        } else {
            dim3 g1(rowblocks, 1);
            k_gemm1_mfma<<<g1, 256, 0, stream>>>(x, W1T, h1c, c0, C, flags);
        }
        if (C == 512) {
            k_agg1_512<<<(NNODES + 3) / 4, 256, 0, stream>>>(h1c, rowptr, csr, dinv, b1c, a1c);
        } else {
            size_t nthr = (size_t)NNODES * (C / 4);
            k_agg1<<<(int)((nthr + 255) / 256), 256, 0, stream>>>(h1c, rowptr, csr, dinv, b1c, c0, C, a1c);
        }
        k_gemm2_v3<<<rowblocks, 256, 0, stream>>>(a1c, C, W2T, c0, h2, chunk_i > 0 ? 1 : 0);
    }

    k_agg2<<<(NNODES + 3) / 4, 256, 0, stream>>>(h2, rowptr, csr, dinv, b2c, d_out, flags);
}